// Round 1
// baseline (10881.656 us; speedup 1.0000x reference)
//
#include <hip/hip_runtime.h>

typedef short s8v __attribute__((ext_vector_type(8)));   // 8 x bf16 bits
typedef float f4v __attribute__((ext_vector_type(4)));
typedef unsigned short u16;

#define CH 128          // timesteps per chunk
#define NCH 4
#define NBLK 256        // k_rec blocks (1 per CU)

__device__ __forceinline__ u16 f2bf(float f) {
  unsigned u = __builtin_bit_cast(unsigned, f);
  u = (u + 0x7fffu + ((u >> 16) & 1u)) >> 16;
  return (u16)u;
}
__device__ __forceinline__ float bf2f(u16 h) {
  unsigned u = ((unsigned)h) << 16;
  return __builtin_bit_cast(float, u);
}

// ---------------- cast inputs to bf16, combine bias ----------------
__global__ void k_cast(const float* __restrict__ x, const float* __restrict__ wih,
                       const float* __restrict__ whh, const float* __restrict__ bih,
                       const float* __restrict__ bhh, u16* __restrict__ xb,
                       u16* __restrict__ wihb, u16* __restrict__ whhb,
                       float* __restrict__ bias) {
  unsigned i = blockIdx.x * 256u + threadIdx.x;          // 2,097,152 threads
  const unsigned NT = 8192u * 256u;
  for (unsigned j = i; j < 8388608u; j += NT) {          // x: 33.5M els as float4
    float4 v = ((const float4*)x)[j];
    ushort4 o; o.x = f2bf(v.x); o.y = f2bf(v.y); o.z = f2bf(v.z); o.w = f2bf(v.w);
    ((ushort4*)xb)[j] = o;
  }
  if (i < 1048576u) {                                    // w_ih, w_hh: 4.19M els each
    float4 v = ((const float4*)wih)[i];
    ushort4 o; o.x = f2bf(v.x); o.y = f2bf(v.y); o.z = f2bf(v.z); o.w = f2bf(v.w);
    ((ushort4*)wihb)[i] = o;
    float4 w = ((const float4*)whh)[i];
    ushort4 p; p.x = f2bf(w.x); p.y = f2bf(w.y); p.z = f2bf(w.z); p.w = f2bf(w.w);
    ((ushort4*)whhb)[i] = p;
  }
  if (i < 4096u) bias[i] = bih[i] + bhh[i];
}

// ---------------- x_proj GEMM (one 128-step chunk): xpn[8192][4096] ----------------
// A = x_bf16 rows (b*512+s0 .. +127) per m-tile b ; B = w_ih rows (nt*128..+127)
__global__ __launch_bounds__(256, 2) void k_gemm(const u16* __restrict__ xb,
                                                 const u16* __restrict__ wihb,
                                                 u16* __restrict__ xpn, int s0) {
  __shared__ u16 lds[16384];                 // A bytes [0,16384), B bytes [16384,32768)
  const int t = threadIdx.x;
  const int bx = blockIdx.x;                 // 2048 = 64 mt * 32 nt
  const int nt = bx & 31, mt = bx >> 5;      // mt == batch b
  const int lane = t & 63, w = t >> 6;
  const int wm = (w >> 1) * 64, wn = (w & 1) * 64;
  const int lr = lane & 15, lk = lane >> 4;
  f4v acc[4][4] = {};
  const size_t arow0 = (size_t)(mt * 512 + s0) * 1024;
  const size_t brow0 = (size_t)(nt * 128) * 1024;
  for (int k0 = 0; k0 < 1024; k0 += 64) {
    #pragma unroll
    for (int i = 0; i < 4; i++) {            // stage A,B tiles [128][64] bf16, XOR swizzled
      int f16 = i * 256 + t;
      int row = f16 >> 3;
      int colb = (f16 & 7) << 4;             // byte col 0..112
      int dst = row * 128 + (colb ^ ((row & 7) << 4));
      s8v va = *(const s8v*)(xb + arow0 + (size_t)row * 1024 + k0 + (colb >> 1));
      *(s8v*)((char*)lds + dst) = va;
      s8v vb = *(const s8v*)(wihb + brow0 + (size_t)row * 1024 + k0 + (colb >> 1));
      *(s8v*)((char*)lds + 16384 + dst) = vb;
    }
    __syncthreads();
    #pragma unroll
    for (int ks = 0; ks < 2; ks++) {
      s8v af[4], bf[4];
      #pragma unroll
      for (int mi = 0; mi < 4; mi++) {
        int r = wm + mi * 16 + lr;
        int cb = (ks * 64 + lk * 16) ^ ((r & 7) << 4);
        af[mi] = *(const s8v*)((const char*)lds + r * 128 + cb);
      }
      #pragma unroll
      for (int ni = 0; ni < 4; ni++) {
        int r = wn + ni * 16 + lr;
        int cb = (ks * 64 + lk * 16) ^ ((r & 7) << 4);
        bf[ni] = *(const s8v*)((const char*)lds + 16384 + r * 128 + cb);
      }
      #pragma unroll
      for (int mi = 0; mi < 4; mi++)
        #pragma unroll
        for (int ni = 0; ni < 4; ni++)
          acc[mi][ni] = __builtin_amdgcn_mfma_f32_16x16x32_bf16(af[mi], bf[ni], acc[mi][ni], 0, 0, 0);
    }
    __syncthreads();
  }
  #pragma unroll
  for (int mi = 0; mi < 4; mi++)
    #pragma unroll
    for (int rr = 0; rr < 4; rr++) {
      int rl = wm + mi * 16 + lk * 4 + rr;                   // chunk-local s
      size_t orow = ((size_t)mt * 128 + rl) * 4096;
      #pragma unroll
      for (int ni = 0; ni < 4; ni++) {
        int col = nt * 128 + wn + ni * 16 + lr;
        xpn[orow + col] = f2bf(acc[mi][ni][rr]);
      }
    }
}

// ------- repack xpn[b*128+s][g*1024+u] -> xpl[s][u>>2][b][u&3][g] (per chunk) -------
__global__ void k_pack(const u16* __restrict__ xpn, u16* __restrict__ xpl) {
  __shared__ u16 lds[32768];
  const int t = threadIdx.x;
  const int bx = blockIdx.x;                 // 1024 = 32 st * 32 ut
  const int ut = bx & 31, st = bx >> 5;
  #pragma unroll
  for (int i = 0; i < 16; i++) {
    int idx = i * 256 + t;
    int c16 = idx & 3, g = (idx >> 2) & 3, b = (idx >> 4) & 63, s = idx >> 10;
    const u16* src = xpn + (size_t)(b * 128 + st * 4 + s) * 4096 + g * 1024 + ut * 32 + c16 * 8;
    s8v v = *(const s8v*)src;
    #pragma unroll
    for (int e = 0; e < 8; e++) {
      int lidx = ((s * 8 + c16 * 2 + (e >> 2)) * 64 + b) * 16 + (e & 3) * 4 + g;
      lds[lidx] = (u16)v[e];
    }
  }
  __syncthreads();
  #pragma unroll
  for (int j = 0; j < 16; j++) {
    int cc = j * 256 + t;
    int within = cc & 127, sb = cc >> 7;
    int s = sb >> 3, ub = sb & 7;
    s8v v = *(const s8v*)(lds + (size_t)(s * 8 + ub) * 1024 + within * 8);
    size_t dst = ((size_t)(st * 4 + s) * 256 + (size_t)ut * 8 + ub) * 1024 + within * 8;
    *(s8v*)(xpl + dst) = v;
  }
}

// ---------------- device-wide barrier (monotonic counter) ----------------
__device__ __forceinline__ void gbar(unsigned* cnt, unsigned target) {
  __syncthreads();
  if (threadIdx.x == 0) {
    __builtin_amdgcn_fence(__ATOMIC_RELEASE, "agent");
    __hip_atomic_fetch_add(cnt, 1u, __ATOMIC_RELAXED, __HIP_MEMORY_SCOPE_AGENT);
    while (__hip_atomic_load(cnt, __ATOMIC_RELAXED, __HIP_MEMORY_SCOPE_AGENT) < target)
      __builtin_amdgcn_s_sleep(1);
    __builtin_amdgcn_fence(__ATOMIC_ACQUIRE, "agent");
  }
  __syncthreads();
}

// ---------------- recurrence: 128 steps, persistent, w_hh in VGPRs ----------------
__global__ __launch_bounds__(256, 1) void k_rec(
    const u16* __restrict__ whhb, const u16* __restrict__ xpl,
    const float* __restrict__ bias, const float* __restrict__ h0,
    const float* __restrict__ c0, float* __restrict__ cst,
    u16* __restrict__ hbuf, float* __restrict__ out,
    unsigned* cnt, int chunk) {
  const int t = threadIdx.x, bid = blockIdx.x;
  const int lane = t & 63, w = t >> 6, lr = lane & 15, lk = lane >> 4;
  // B fragments: 16 gate cols (n = g*4+u'), K=1024 -> 32 frags, kept in VGPRs
  s8v breg[32];
  {
    int grow = (lr >> 2) * 1024 + bid * 4 + (lr & 3);      // w_hh row for col n=lr
    const u16* wp = whhb + (size_t)grow * 1024 + lk * 8;
    #pragma unroll
    for (int ks = 0; ks < 32; ks++) breg[ks] = *(const s8v*)(wp + ks * 32);
  }
  const int em = t >> 2, eu = t & 3;                        // elementwise: (batch m, unit u')
  const int gu = bid * 4 + eu;                              // global hidden unit
  const float bi = bias[gu], bff = bias[1024 + gu], bg = bias[2048 + gu], bo = bias[3072 + gu];
  float c;
  unsigned barn = 0;
  if (chunk == 0) {
    c = c0[em * 1024 + gu];
    hbuf[em * 1024 + gu] = f2bf(h0[em * 1024 + gu]);
    barn++; gbar(cnt, barn * NBLK);
  } else {
    c = cst[em * 1024 + gu];
  }
  __shared__ float gl[1024];                                // gates [64 m][16 n] f32
  int cur = 0;
  for (int tl = 0; tl < CH; tl++) {
    ushort4 xpv = *(const ushort4*)(xpl + (size_t)tl * 262144 + bid * 1024 + t * 4);
    const u16* ap = hbuf + cur * 65536 + (w * 16 + lr) * 1024 + lk * 8;
    f4v acc = {0.f, 0.f, 0.f, 0.f};
    #pragma unroll
    for (int ks = 0; ks < 32; ks++) {
      s8v a = *(const s8v*)(ap + ks * 32);
      acc = __builtin_amdgcn_mfma_f32_16x16x32_bf16(a, breg[ks], acc, 0, 0, 0);
    }
    #pragma unroll
    for (int r = 0; r < 4; r++) gl[(w * 16 + lk * 4 + r) * 16 + lr] = acc[r];
    __syncthreads();
    float pi = gl[em * 16 + 0 + eu] + bf2f(xpv.x) + bi;
    float pf = gl[em * 16 + 4 + eu] + bf2f(xpv.y) + bff;
    float pg = gl[em * 16 + 8 + eu] + bf2f(xpv.z) + bg;
    float po = gl[em * 16 + 12 + eu] + bf2f(xpv.w) + bo;
    float iv = 1.f / (1.f + __expf(-pi));
    float fv = 1.f / (1.f + __expf(-pf));
    float ev = __expf(2.f * pg);
    float gv = 1.f - 2.f / (ev + 1.f);
    float ov = 1.f / (1.f + __expf(-po));
    c = fv * c + iv * gv;
    float e2 = __expf(2.f * c);
    float hv = ov * (1.f - 2.f / (e2 + 1.f));
    int nxt = cur ^ 1;
    hbuf[nxt * 65536 + em * 1024 + gu] = f2bf(hv);
    cur = nxt;
    if (tl < CH - 1) {
      barn++; gbar(cnt, barn * NBLK);
    } else {
      if (chunk == NCH - 1) out[em * 1024 + gu] = hv;
      else cst[em * 1024 + gu] = c;
    }
  }
}

extern "C" void kernel_launch(void* const* d_in, const int* in_sizes, int n_in,
                              void* d_out, int out_size, void* d_ws, size_t ws_size,
                              hipStream_t stream) {
  const float* x   = (const float*)d_in[0];
  const float* h0  = (const float*)d_in[1];
  const float* c0  = (const float*)d_in[2];
  const float* wih = (const float*)d_in[3];
  const float* whh = (const float*)d_in[4];
  const float* bih = (const float*)d_in[5];
  const float* bhh = (const float*)d_in[6];
  float* out = (float*)d_out;
  char* ws = (char*)d_ws;
  u16* xb     = (u16*)(ws);                       // 64 MB  x bf16
  u16* wihb   = (u16*)(ws + 67108864);            // 8 MB
  u16* whhb   = (u16*)(ws + 75497472);            // 8 MB
  float* bias = (float*)(ws + 83886080);          // 16 KB
  u16* hbuf   = (u16*)(ws + 83902464);            // 256 KB (2 buffers)
  float* cst  = (float*)(ws + 84164608);          // 256 KB
  unsigned* cnt = (unsigned*)(ws + 84426752);     // 256 B
  u16* xpn    = (u16*)(ws + 84427008);            // 64 MB per-chunk x_proj (natural)
  u16* xpl    = (u16*)(ws + 151535872);           // 64 MB per-chunk x_proj (packed) -> end 218,644,736
  (void)in_sizes; (void)n_in; (void)out_size; (void)ws_size;

  hipLaunchKernelGGL(k_cast, dim3(8192), dim3(256), 0, stream,
                     x, wih, whh, bih, bhh, xb, wihb, whhb, bias);
  for (int c = 0; c < NCH; c++) {
    hipLaunchKernelGGL(k_gemm, dim3(2048), dim3(256), 0, stream, xb, wihb, xpn, c * CH);
    hipLaunchKernelGGL(k_pack, dim3(1024), dim3(256), 0, stream, xpn, xpl);
    hipMemsetAsync(cnt, 0, 256, stream);
    hipLaunchKernelGGL(k_rec, dim3(NBLK), dim3(256), 0, stream,
                       whhb, xpl, bias, h0, c0, cst, hbuf, out, cnt, c);
  }
}

// Round 2
// 8009.437 us; speedup vs baseline: 1.3586x; 1.3586x over previous
//
#include <hip/hip_runtime.h>

typedef short s8v __attribute__((ext_vector_type(8)));   // 8 x bf16 bits
typedef float f4v __attribute__((ext_vector_type(4)));
typedef unsigned short u16;

#define CH 128          // timesteps per chunk
#define NCH 4
#define NBLK 256        // k_rec blocks (1 per CU)

__device__ __forceinline__ u16 f2bf(float f) {
  unsigned u = __builtin_bit_cast(unsigned, f);
  u = (u + 0x7fffu + ((u >> 16) & 1u)) >> 16;
  return (u16)u;
}
__device__ __forceinline__ float bf2f(u16 h) {
  unsigned u = ((unsigned)h) << 16;
  return __builtin_bit_cast(float, u);
}

// ---------------- cast inputs to bf16, combine bias ----------------
__global__ void k_cast(const float* __restrict__ x, const float* __restrict__ wih,
                       const float* __restrict__ whh, const float* __restrict__ bih,
                       const float* __restrict__ bhh, u16* __restrict__ xb,
                       u16* __restrict__ wihb, u16* __restrict__ whhb,
                       float* __restrict__ bias) {
  unsigned i = blockIdx.x * 256u + threadIdx.x;          // 2,097,152 threads
  const unsigned NT = 8192u * 256u;
  for (unsigned j = i; j < 8388608u; j += NT) {          // x: 33.5M els as float4
    float4 v = ((const float4*)x)[j];
    ushort4 o; o.x = f2bf(v.x); o.y = f2bf(v.y); o.z = f2bf(v.z); o.w = f2bf(v.w);
    ((ushort4*)xb)[j] = o;
  }
  if (i < 1048576u) {                                    // w_ih, w_hh: 4.19M els each
    float4 v = ((const float4*)wih)[i];
    ushort4 o; o.x = f2bf(v.x); o.y = f2bf(v.y); o.z = f2bf(v.z); o.w = f2bf(v.w);
    ((ushort4*)wihb)[i] = o;
    float4 w = ((const float4*)whh)[i];
    ushort4 p; p.x = f2bf(w.x); p.y = f2bf(w.y); p.z = f2bf(w.z); p.w = f2bf(w.w);
    ((ushort4*)whhb)[i] = p;
  }
  if (i < 4096u) bias[i] = bih[i] + bhh[i];
}

// ---------------- x_proj GEMM (one 128-step chunk): xpn[8192][4096] ----------------
__global__ __launch_bounds__(256, 2) void k_gemm(const u16* __restrict__ xb,
                                                 const u16* __restrict__ wihb,
                                                 u16* __restrict__ xpn, int s0) {
  __shared__ u16 lds[16384];                 // A bytes [0,16384), B bytes [16384,32768)
  const int t = threadIdx.x;
  const int bx = blockIdx.x;                 // 2048 = 64 mt * 32 nt
  const int nt = bx & 31, mt = bx >> 5;      // mt == batch b
  const int lane = t & 63, w = t >> 6;
  const int wm = (w >> 1) * 64, wn = (w & 1) * 64;
  const int lr = lane & 15, lk = lane >> 4;
  f4v acc[4][4] = {};
  const size_t arow0 = (size_t)(mt * 512 + s0) * 1024;
  const size_t brow0 = (size_t)(nt * 128) * 1024;
  for (int k0 = 0; k0 < 1024; k0 += 64) {
    #pragma unroll
    for (int i = 0; i < 4; i++) {            // stage A,B tiles [128][64] bf16, XOR swizzled
      int f16 = i * 256 + t;
      int row = f16 >> 3;
      int colb = (f16 & 7) << 4;             // byte col 0..112
      int dst = row * 128 + (colb ^ ((row & 7) << 4));
      s8v va = *(const s8v*)(xb + arow0 + (size_t)row * 1024 + k0 + (colb >> 1));
      *(s8v*)((char*)lds + dst) = va;
      s8v vb = *(const s8v*)(wihb + brow0 + (size_t)row * 1024 + k0 + (colb >> 1));
      *(s8v*)((char*)lds + 16384 + dst) = vb;
    }
    __syncthreads();
    #pragma unroll
    for (int ks = 0; ks < 2; ks++) {
      s8v af[4], bf[4];
      #pragma unroll
      for (int mi = 0; mi < 4; mi++) {
        int r = wm + mi * 16 + lr;
        int cb = (ks * 64 + lk * 16) ^ ((r & 7) << 4);
        af[mi] = *(const s8v*)((const char*)lds + r * 128 + cb);
      }
      #pragma unroll
      for (int ni = 0; ni < 4; ni++) {
        int r = wn + ni * 16 + lr;
        int cb = (ks * 64 + lk * 16) ^ ((r & 7) << 4);
        bf[ni] = *(const s8v*)((const char*)lds + 16384 + r * 128 + cb);
      }
      #pragma unroll
      for (int mi = 0; mi < 4; mi++)
        #pragma unroll
        for (int ni = 0; ni < 4; ni++)
          acc[mi][ni] = __builtin_amdgcn_mfma_f32_16x16x32_bf16(af[mi], bf[ni], acc[mi][ni], 0, 0, 0);
    }
    __syncthreads();
  }
  #pragma unroll
  for (int mi = 0; mi < 4; mi++)
    #pragma unroll
    for (int rr = 0; rr < 4; rr++) {
      int rl = wm + mi * 16 + lk * 4 + rr;                   // chunk-local s
      size_t orow = ((size_t)mt * 128 + rl) * 4096;
      #pragma unroll
      for (int ni = 0; ni < 4; ni++) {
        int col = nt * 128 + wn + ni * 16 + lr;
        xpn[orow + col] = f2bf(acc[mi][ni][rr]);
      }
    }
}

// ------- repack xpn[b*128+s][g*1024+u] -> xpl[s][u>>2][b][u&3][g] (per chunk) -------
__global__ void k_pack(const u16* __restrict__ xpn, u16* __restrict__ xpl) {
  __shared__ u16 lds[32768];
  const int t = threadIdx.x;
  const int bx = blockIdx.x;                 // 1024 = 32 st * 32 ut
  const int ut = bx & 31, st = bx >> 5;
  #pragma unroll
  for (int i = 0; i < 16; i++) {
    int idx = i * 256 + t;
    int c16 = idx & 3, g = (idx >> 2) & 3, b = (idx >> 4) & 63, s = idx >> 10;
    const u16* src = xpn + (size_t)(b * 128 + st * 4 + s) * 4096 + g * 1024 + ut * 32 + c16 * 8;
    s8v v = *(const s8v*)src;
    #pragma unroll
    for (int e = 0; e < 8; e++) {
      int lidx = ((s * 8 + c16 * 2 + (e >> 2)) * 64 + b) * 16 + (e & 3) * 4 + g;
      lds[lidx] = (u16)v[e];
    }
  }
  __syncthreads();
  #pragma unroll
  for (int j = 0; j < 16; j++) {
    int cc = j * 256 + t;
    int within = cc & 127, sb = cc >> 7;
    int s = sb >> 3, ub = sb & 7;
    s8v v = *(const s8v*)(lds + (size_t)(s * 8 + ub) * 1024 + within * 8);
    size_t dst = ((size_t)(st * 4 + s) * 256 + (size_t)ut * 8 + ub) * 1024 + within * 8;
    *(s8v*)(xpl + dst) = v;
  }
}

// -------- device-wide barrier: distributed per-block flags, no contended RMW --------
// flags[b*16] (64B stride). Each block release-stores its epoch, then wave 0 of
// every block polls all 256 flags (4 per lane) until all >= ep.
__device__ __forceinline__ void gbar2(unsigned* flags, unsigned ep) {
  __syncthreads();                            // drains vmcnt: h stores are in L2
  if (threadIdx.x < 64) {
    if (threadIdx.x == 0) {
      __builtin_amdgcn_fence(__ATOMIC_RELEASE, "agent");   // writeback to coherence point
      __hip_atomic_store(flags + (size_t)blockIdx.x * 16, ep,
                         __ATOMIC_RELAXED, __HIP_MEMORY_SCOPE_AGENT);
    }
    const int l = threadIdx.x;
    for (;;) {
      unsigned a = __hip_atomic_load(flags + l * 16,         __ATOMIC_RELAXED, __HIP_MEMORY_SCOPE_AGENT);
      unsigned b = __hip_atomic_load(flags + (l + 64) * 16,  __ATOMIC_RELAXED, __HIP_MEMORY_SCOPE_AGENT);
      unsigned c = __hip_atomic_load(flags + (l + 128) * 16, __ATOMIC_RELAXED, __HIP_MEMORY_SCOPE_AGENT);
      unsigned d = __hip_atomic_load(flags + (l + 192) * 16, __ATOMIC_RELAXED, __HIP_MEMORY_SCOPE_AGENT);
      if (__all(a >= ep && b >= ep && c >= ep && d >= ep)) break;
    }
    if (threadIdx.x == 0)
      __builtin_amdgcn_fence(__ATOMIC_ACQUIRE, "agent");     // invalidate stale h
  }
  __syncthreads();
}

// ---------------- recurrence: 128 steps, persistent, w_hh in VGPRs ----------------
__global__ __launch_bounds__(256, 1) void k_rec(
    const u16* __restrict__ whhb, const u16* __restrict__ xpl,
    const float* __restrict__ bias, const float* __restrict__ h0,
    const float* __restrict__ c0, float* __restrict__ cst,
    u16* __restrict__ hbuf, float* __restrict__ out,
    unsigned* flags, int chunk) {
  const int t = threadIdx.x, bid = blockIdx.x;
  const int lane = t & 63, w = t >> 6, lr = lane & 15, lk = lane >> 4;
  // B fragments: 16 gate cols (n = g*4+u'), K=1024 -> 32 frags, kept in VGPRs
  s8v breg[32];
  {
    int grow = (lr >> 2) * 1024 + bid * 4 + (lr & 3);      // w_hh row for col n=lr
    const u16* wp = whhb + (size_t)grow * 1024 + lk * 8;
    #pragma unroll
    for (int ks = 0; ks < 32; ks++) breg[ks] = *(const s8v*)(wp + ks * 32);
  }
  const int em = t >> 2, eu = t & 3;                        // elementwise: (batch m, unit u')
  const int gu = bid * 4 + eu;                              // global hidden unit
  const float bi = bias[gu], bff = bias[1024 + gu], bg = bias[2048 + gu], bo = bias[3072 + gu];
  float c;
  unsigned barn = 0;
  if (chunk == 0) {
    c = c0[em * 1024 + gu];
    hbuf[em * 1024 + gu] = f2bf(h0[em * 1024 + gu]);
    barn++; gbar2(flags, barn);
  } else {
    c = cst[em * 1024 + gu];
  }
  __shared__ float gl[1024];                                // gates [64 m][16 n] f32
  int cur = 0;
  for (int tl = 0; tl < CH; tl++) {
    ushort4 xpv = *(const ushort4*)(xpl + (size_t)tl * 262144 + bid * 1024 + t * 4);
    const u16* ap = hbuf + cur * 65536 + (w * 16 + lr) * 1024 + lk * 8;
    f4v acc = {0.f, 0.f, 0.f, 0.f};
    #pragma unroll
    for (int ks = 0; ks < 32; ks++) {
      s8v a = *(const s8v*)(ap + ks * 32);
      acc = __builtin_amdgcn_mfma_f32_16x16x32_bf16(a, breg[ks], acc, 0, 0, 0);
    }
    #pragma unroll
    for (int r = 0; r < 4; r++) gl[(w * 16 + lk * 4 + r) * 16 + lr] = acc[r];
    __syncthreads();
    float pi = gl[em * 16 + 0 + eu] + bf2f(xpv.x) + bi;
    float pf = gl[em * 16 + 4 + eu] + bf2f(xpv.y) + bff;
    float pg = gl[em * 16 + 8 + eu] + bf2f(xpv.z) + bg;
    float po = gl[em * 16 + 12 + eu] + bf2f(xpv.w) + bo;
    float iv = 1.f / (1.f + __expf(-pi));
    float fv = 1.f / (1.f + __expf(-pf));
    float ev = __expf(2.f * pg);
    float gv = 1.f - 2.f / (ev + 1.f);
    float ov = 1.f / (1.f + __expf(-po));
    c = fv * c + iv * gv;
    float e2 = __expf(2.f * c);
    float hv = ov * (1.f - 2.f / (e2 + 1.f));
    int nxt = cur ^ 1;
    hbuf[nxt * 65536 + em * 1024 + gu] = f2bf(hv);
    cur = nxt;
    if (tl < CH - 1) {
      barn++; gbar2(flags, barn);
    } else {
      if (chunk == NCH - 1) out[em * 1024 + gu] = hv;
      else cst[em * 1024 + gu] = c;
    }
  }
}

extern "C" void kernel_launch(void* const* d_in, const int* in_sizes, int n_in,
                              void* d_out, int out_size, void* d_ws, size_t ws_size,
                              hipStream_t stream) {
  const float* x   = (const float*)d_in[0];
  const float* h0  = (const float*)d_in[1];
  const float* c0  = (const float*)d_in[2];
  const float* wih = (const float*)d_in[3];
  const float* whh = (const float*)d_in[4];
  const float* bih = (const float*)d_in[5];
  const float* bhh = (const float*)d_in[6];
  float* out = (float*)d_out;
  char* ws = (char*)d_ws;
  u16* xb     = (u16*)(ws);                       // 64 MB  x bf16
  u16* wihb   = (u16*)(ws + 67108864);            // 8 MB
  u16* whhb   = (u16*)(ws + 75497472);            // 8 MB
  float* bias = (float*)(ws + 83886080);          // 16 KB
  u16* hbuf   = (u16*)(ws + 83902464);            // 256 KB (2 buffers)
  float* cst  = (float*)(ws + 84164608);          // 256 KB
  unsigned* flags = (unsigned*)(ws + 84426752);   // 16 KB (256 x 64B)
  u16* xpn    = (u16*)(ws + 84443136);            // 64 MB per-chunk x_proj (natural)
  u16* xpl    = (u16*)(ws + 151552000);           // 64 MB per-chunk x_proj (packed)
  (void)in_sizes; (void)n_in; (void)out_size; (void)ws_size;

  hipLaunchKernelGGL(k_cast, dim3(8192), dim3(256), 0, stream,
                     x, wih, whh, bih, bhh, xb, wihb, whhb, bias);
  for (int c = 0; c < NCH; c++) {
    hipLaunchKernelGGL(k_gemm, dim3(2048), dim3(256), 0, stream, xb, wihb, xpn, c * CH);
    hipLaunchKernelGGL(k_pack, dim3(1024), dim3(256), 0, stream, xpn, xpl);
    hipMemsetAsync(flags, 0, 16384, stream);
    hipLaunchKernelGGL(k_rec, dim3(NBLK), dim3(256), 0, stream,
                       whhb, xpl, bias, h0, c0, cst, hbuf, out, flags, c);
  }
}

// Round 3
// 3833.498 us; speedup vs baseline: 2.8386x; 2.0893x over previous
//
#include <hip/hip_runtime.h>

typedef short s8v __attribute__((ext_vector_type(8)));   // 8 x bf16 bits
typedef float f4v __attribute__((ext_vector_type(4)));
typedef unsigned short u16;

#define CH 128          // timesteps per chunk
#define NCH 4
#define NBLK 128        // k_rec blocks; each owns 8 hidden units (32 gate cols)

__device__ __forceinline__ u16 f2bf(float f) {
  unsigned u = __builtin_bit_cast(unsigned, f);
  u = (u + 0x7fffu + ((u >> 16) & 1u)) >> 16;
  return (u16)u;
}
__device__ __forceinline__ float bf2f(u16 h) {
  unsigned u = ((unsigned)h) << 16;
  return __builtin_bit_cast(float, u);
}

// ---------------- cast inputs to bf16, combine bias ----------------
__global__ void k_cast(const float* __restrict__ x, const float* __restrict__ wih,
                       const float* __restrict__ whh, const float* __restrict__ bih,
                       const float* __restrict__ bhh, u16* __restrict__ xb,
                       u16* __restrict__ wihb, u16* __restrict__ whhb,
                       float* __restrict__ bias) {
  unsigned i = blockIdx.x * 256u + threadIdx.x;
  const unsigned NT = 8192u * 256u;
  for (unsigned j = i; j < 8388608u; j += NT) {          // x: 33.5M els as float4
    float4 v = ((const float4*)x)[j];
    ushort4 o; o.x = f2bf(v.x); o.y = f2bf(v.y); o.z = f2bf(v.z); o.w = f2bf(v.w);
    ((ushort4*)xb)[j] = o;
  }
  if (i < 1048576u) {                                    // w_ih, w_hh
    float4 v = ((const float4*)wih)[i];
    ushort4 o; o.x = f2bf(v.x); o.y = f2bf(v.y); o.z = f2bf(v.z); o.w = f2bf(v.w);
    ((ushort4*)wihb)[i] = o;
    float4 w = ((const float4*)whh)[i];
    ushort4 p; p.x = f2bf(w.x); p.y = f2bf(w.y); p.z = f2bf(w.z); p.w = f2bf(w.w);
    ((ushort4*)whhb)[i] = p;
  }
  if (i < 4096u) bias[i] = bih[i] + bhh[i];
}

// ---------------- x_proj GEMM (one 128-step chunk): xpn[8192][4096] ----------------
__global__ __launch_bounds__(256, 2) void k_gemm(const u16* __restrict__ xb,
                                                 const u16* __restrict__ wihb,
                                                 u16* __restrict__ xpn, int s0) {
  __shared__ u16 lds[16384];
  const int t = threadIdx.x;
  const int bx = blockIdx.x;                 // 2048 = 64 mt * 32 nt
  const int nt = bx & 31, mt = bx >> 5;
  const int lane = t & 63, w = t >> 6;
  const int wm = (w >> 1) * 64, wn = (w & 1) * 64;
  const int lr = lane & 15, lk = lane >> 4;
  f4v acc[4][4] = {};
  const size_t arow0 = (size_t)(mt * 512 + s0) * 1024;
  const size_t brow0 = (size_t)(nt * 128) * 1024;
  for (int k0 = 0; k0 < 1024; k0 += 64) {
    #pragma unroll
    for (int i = 0; i < 4; i++) {
      int f16 = i * 256 + t;
      int row = f16 >> 3;
      int colb = (f16 & 7) << 4;
      int dst = row * 128 + (colb ^ ((row & 7) << 4));
      s8v va = *(const s8v*)(xb + arow0 + (size_t)row * 1024 + k0 + (colb >> 1));
      *(s8v*)((char*)lds + dst) = va;
      s8v vb = *(const s8v*)(wihb + brow0 + (size_t)row * 1024 + k0 + (colb >> 1));
      *(s8v*)((char*)lds + 16384 + dst) = vb;
    }
    __syncthreads();
    #pragma unroll
    for (int ks = 0; ks < 2; ks++) {
      s8v af[4], bf[4];
      #pragma unroll
      for (int mi = 0; mi < 4; mi++) {
        int r = wm + mi * 16 + lr;
        int cb = (ks * 64 + lk * 16) ^ ((r & 7) << 4);
        af[mi] = *(const s8v*)((const char*)lds + r * 128 + cb);
      }
      #pragma unroll
      for (int ni = 0; ni < 4; ni++) {
        int r = wn + ni * 16 + lr;
        int cb = (ks * 64 + lk * 16) ^ ((r & 7) << 4);
        bf[ni] = *(const s8v*)((const char*)lds + 16384 + r * 128 + cb);
      }
      #pragma unroll
      for (int mi = 0; mi < 4; mi++)
        #pragma unroll
        for (int ni = 0; ni < 4; ni++)
          acc[mi][ni] = __builtin_amdgcn_mfma_f32_16x16x32_bf16(af[mi], bf[ni], acc[mi][ni], 0, 0, 0);
    }
    __syncthreads();
  }
  #pragma unroll
  for (int mi = 0; mi < 4; mi++)
    #pragma unroll
    for (int rr = 0; rr < 4; rr++) {
      int rl = wm + mi * 16 + lk * 4 + rr;
      size_t orow = ((size_t)mt * 128 + rl) * 4096;
      #pragma unroll
      for (int ni = 0; ni < 4; ni++) {
        int col = nt * 128 + wn + ni * 16 + lr;
        xpn[orow + col] = f2bf(acc[mi][ni][rr]);
      }
    }
}

// ---- repack xpn[b*128+s][g*1024+u] -> xpl[((s*128+ub)*4+g)*512 + b*8 + u'] ----
// (pure 16B copies; ub = u>>3, u' = u&7)
__global__ void k_pack(const u16* __restrict__ xpn, u16* __restrict__ xpl) {
  const int t = threadIdx.x;
  const int bx = blockIdx.x;                 // 2048 = 128 s * 16 ubg
  const int s = bx >> 4, ubg = bx & 15;
  const int g = t & 3, b = t >> 2;
  #pragma unroll
  for (int i = 0; i < 8; i++) {
    int ub = ubg * 8 + i;
    s8v v = *(const s8v*)(xpn + (size_t)(b * 128 + s) * 4096 + g * 1024 + ub * 8);
    *(s8v*)(xpl + (((size_t)s * 128 + ub) * 4 + g) * 512 + b * 8) = v;
  }
}

// ------- device-wide barrier: per-block flags at LLC, NO fences -------
__device__ __forceinline__ void gbar2(unsigned* flags, unsigned ep) {
  __syncthreads();                            // all waves drained vmcnt before barrier
  if (threadIdx.x < 64) {
    if (threadIdx.x == 0)
      __hip_atomic_store(flags + (size_t)blockIdx.x * 16, ep,
                         __ATOMIC_RELAXED, __HIP_MEMORY_SCOPE_AGENT);
    const int l = threadIdx.x;
    for (;;) {
      unsigned a = __hip_atomic_load(flags + l * 16,        __ATOMIC_RELAXED, __HIP_MEMORY_SCOPE_AGENT);
      unsigned b = __hip_atomic_load(flags + (l + 64) * 16, __ATOMIC_RELAXED, __HIP_MEMORY_SCOPE_AGENT);
      if (__all(a >= ep && b >= ep)) break;
    }
  }
  __syncthreads();
}

// ---------------- recurrence: persistent, fence-free LLC h-exchange ----------------
__global__ __launch_bounds__(256, 1) void k_rec(
    const u16* __restrict__ whhb, const u16* __restrict__ xpl,
    const float* __restrict__ bias, const float* __restrict__ h0,
    const float* __restrict__ c0, float* __restrict__ cst,
    u16* __restrict__ hbuf, float* __restrict__ out,
    unsigned* flags, int chunk) {
  const int t = threadIdx.x, bid = blockIdx.x;
  const int lane = t & 63, w = t >> 6, lr = lane & 15, lk = lane >> 4;
  // B fragments: 2 n-tiles x 32 k-frags (cols: gate=lr>>2, unit=bid*8+nt*4+(lr&3))
  s8v breg[2][32];
  #pragma unroll
  for (int nt = 0; nt < 2; nt++) {
    int grow = (lr >> 2) * 1024 + bid * 8 + nt * 4 + (lr & 3);
    const u16* wp = whhb + (size_t)grow * 1024 + lk * 8;
    #pragma unroll
    for (int ks = 0; ks < 32; ks++) breg[nt][ks] = *(const s8v*)(wp + ks * 32);
  }
  const int m = t >> 2, up = t & 3;          // elementwise role: batch m, unit pair up
  const int gu0 = bid * 8 + up * 2;          // first of 2 global hidden units
  const float2 bi  = *(const float2*)(bias + gu0);
  const float2 bff = *(const float2*)(bias + 1024 + gu0);
  const float2 bgg = *(const float2*)(bias + 2048 + gu0);
  const float2 bo  = *(const float2*)(bias + 3072 + gu0);
  float2 c;
  unsigned barn = 0;
  if (chunk == 0) {
    c = *(const float2*)(c0 + m * 1024 + gu0);
    float2 hv = *(const float2*)(h0 + m * 1024 + gu0);
    unsigned hw = (unsigned)f2bf(hv.x) | ((unsigned)f2bf(hv.y) << 16);
    asm volatile("global_store_dword %0, %1, off sc0 sc1"
                 :: "v"(hbuf + m * 1024 + gu0), "v"(hw) : "memory");
    asm volatile("s_waitcnt vmcnt(0)" ::: "memory");
    barn++; gbar2(flags, barn);
  } else {
    c = *(const float2*)(cst + m * 1024 + gu0);
  }
  __shared__ float gl[2048];                 // gates [64 m][8 u][4 g] f32
  int cur = 0;
  for (int tl = 0; tl < CH; tl++) {
    // xpl loads (cached path, via asm so vmcnt bookkeeping stays manual)
    const u16* xb_ = xpl + ((size_t)tl * 128 + bid) * 2048;
    unsigned xpr[4];
    #pragma unroll
    for (int g = 0; g < 4; g++)
      asm volatile("global_load_dword %0, %1, off"
                   : "=v"(xpr[g]) : "v"(xb_ + g * 512 + m * 8 + up * 2) : "memory");
    // h fragment loads, sc0 sc1 (LLC-coherent)
    const u16* ap = hbuf + cur * 65536 + (w * 16 + lr) * 1024 + lk * 8;
    s8v af[32];
    #pragma unroll
    for (int ks = 0; ks < 32; ks++)
      asm volatile("global_load_dwordx4 %0, %1, off sc0 sc1"
                   : "=v"(af[ks]) : "v"(ap + ks * 32) : "memory");
    f4v acc0 = {0.f, 0.f, 0.f, 0.f}, acc1 = {0.f, 0.f, 0.f, 0.f};
    asm volatile("s_waitcnt vmcnt(16)" ::: "memory");
    __builtin_amdgcn_sched_barrier(0);
    #pragma unroll
    for (int ks = 0; ks < 16; ks++) {
      acc0 = __builtin_amdgcn_mfma_f32_16x16x32_bf16(af[ks], breg[0][ks], acc0, 0, 0, 0);
      acc1 = __builtin_amdgcn_mfma_f32_16x16x32_bf16(af[ks], breg[1][ks], acc1, 0, 0, 0);
    }
    asm volatile("s_waitcnt vmcnt(0)" ::: "memory");
    __builtin_amdgcn_sched_barrier(0);
    #pragma unroll
    for (int ks = 16; ks < 32; ks++) {
      acc0 = __builtin_amdgcn_mfma_f32_16x16x32_bf16(af[ks], breg[0][ks], acc0, 0, 0, 0);
      acc1 = __builtin_amdgcn_mfma_f32_16x16x32_bf16(af[ks], breg[1][ks], acc1, 0, 0, 0);
    }
    // acc -> LDS: gl[m*32 + u*4 + g]
    #pragma unroll
    for (int r = 0; r < 4; r++) {
      int mrow = w * 16 + lk * 4 + r;
      gl[mrow * 32 + ((lr & 3)) * 4 + (lr >> 2)] = acc0[r];
      gl[mrow * 32 + (4 + (lr & 3)) * 4 + (lr >> 2)] = acc1[r];
    }
    __syncthreads();
    float4 q0 = *(const float4*)(gl + m * 32 + up * 8);      // u0: i,f,g,o
    float4 q1 = *(const float4*)(gl + m * 32 + up * 8 + 4);  // u1: i,f,g,o
    float pi0 = q0.x + bf2f((u16)(xpr[0] & 0xffff)) + bi.x;
    float pf0 = q0.y + bf2f((u16)(xpr[1] & 0xffff)) + bff.x;
    float pg0 = q0.z + bf2f((u16)(xpr[2] & 0xffff)) + bgg.x;
    float po0 = q0.w + bf2f((u16)(xpr[3] & 0xffff)) + bo.x;
    float pi1 = q1.x + bf2f((u16)(xpr[0] >> 16)) + bi.y;
    float pf1 = q1.y + bf2f((u16)(xpr[1] >> 16)) + bff.y;
    float pg1 = q1.z + bf2f((u16)(xpr[2] >> 16)) + bgg.y;
    float po1 = q1.w + bf2f((u16)(xpr[3] >> 16)) + bo.y;
    float i0 = 1.f / (1.f + __expf(-pi0)), i1 = 1.f / (1.f + __expf(-pi1));
    float f0 = 1.f / (1.f + __expf(-pf0)), f1 = 1.f / (1.f + __expf(-pf1));
    float g0 = 1.f - 2.f / (__expf(2.f * pg0) + 1.f), g1 = 1.f - 2.f / (__expf(2.f * pg1) + 1.f);
    float o0 = 1.f / (1.f + __expf(-po0)), o1 = 1.f / (1.f + __expf(-po1));
    c.x = f0 * c.x + i0 * g0;
    c.y = f1 * c.y + i1 * g1;
    float hv0 = o0 * (1.f - 2.f / (__expf(2.f * c.x) + 1.f));
    float hv1 = o1 * (1.f - 2.f / (__expf(2.f * c.y) + 1.f));
    int nxt = cur ^ 1;
    unsigned hw = (unsigned)f2bf(hv0) | ((unsigned)f2bf(hv1) << 16);
    asm volatile("global_store_dword %0, %1, off sc0 sc1"
                 :: "v"(hbuf + nxt * 65536 + m * 1024 + gu0), "v"(hw) : "memory");
    cur = nxt;
    if (tl < CH - 1) {
      asm volatile("s_waitcnt vmcnt(0)" ::: "memory");
      barn++; gbar2(flags, barn);
    } else {
      if (chunk == NCH - 1) *(float2*)(out + m * 1024 + gu0) = make_float2(hv0, hv1);
      else *(float2*)(cst + m * 1024 + gu0) = c;
    }
  }
}

extern "C" void kernel_launch(void* const* d_in, const int* in_sizes, int n_in,
                              void* d_out, int out_size, void* d_ws, size_t ws_size,
                              hipStream_t stream) {
  const float* x   = (const float*)d_in[0];
  const float* h0  = (const float*)d_in[1];
  const float* c0  = (const float*)d_in[2];
  const float* wih = (const float*)d_in[3];
  const float* whh = (const float*)d_in[4];
  const float* bih = (const float*)d_in[5];
  const float* bhh = (const float*)d_in[6];
  float* out = (float*)d_out;
  char* ws = (char*)d_ws;
  u16* xb     = (u16*)(ws);                       // 64 MB  x bf16
  u16* wihb   = (u16*)(ws + 67108864);            // 8 MB
  u16* whhb   = (u16*)(ws + 75497472);            // 8 MB
  float* bias = (float*)(ws + 83886080);          // 16 KB
  u16* hbuf   = (u16*)(ws + 83902464);            // 256 KB (2 buffers)
  float* cst  = (float*)(ws + 84164608);          // 256 KB
  unsigned* flags = (unsigned*)(ws + 84426752);   // 16 KB (flag/64B)
  u16* xpn    = (u16*)(ws + 84443136);            // 64 MB per-chunk x_proj (natural)
  u16* xpl    = (u16*)(ws + 151552000);           // 64 MB per-chunk x_proj (packed)
  (void)in_sizes; (void)n_in; (void)out_size; (void)ws_size;

  hipLaunchKernelGGL(k_cast, dim3(8192), dim3(256), 0, stream,
                     x, wih, whh, bih, bhh, xb, wihb, whhb, bias);
  for (int c = 0; c < NCH; c++) {
    hipLaunchKernelGGL(k_gemm, dim3(2048), dim3(256), 0, stream, xb, wihb, xpn, c * CH);
    hipLaunchKernelGGL(k_pack, dim3(2048), dim3(256), 0, stream, xpn, xpl);
    hipMemsetAsync(flags, 0, 16384, stream);
    hipLaunchKernelGGL(k_rec, dim3(NBLK), dim3(256), 0, stream,
                       whhb, xpl, bias, h0, c0, cst, hbuf, out, flags, c);
  }
}